// Round 21
// baseline (172.720 us; speedup 1.0000x reference)
//
#include <hip/hip_runtime.h>
#include <hip/hip_bf16.h>

// MHA forward: B=4, S=2048, D=1024, H=16, DH=64. fp32 in/out, bf16 MFMA inside.

#define Bq 4
#define Sq 2048
#define Dq 1024
#define Hq 16
#define DHq 64

typedef __attribute__((ext_vector_type(8))) short short8;
typedef __attribute__((ext_vector_type(4))) float f32x4;
typedef __attribute__((ext_vector_type(2))) unsigned int uint2v;

static __device__ __forceinline__ unsigned short f2bfu(float f) {
    union { __hip_bfloat16 h; unsigned short u; } cv;
    cv.h = __float2bfloat16(f);
    return cv.u;
}
static __device__ __forceinline__ unsigned int cvtpk(float lo, float hi) {
    unsigned int r;
    asm("v_cvt_pk_bf16_f32 %0, %1, %2" : "=v"(r) : "v"(lo), "v"(hi));
    return r;
}

// ---------------------------------------------------------------------------
// Kernel 0: fp32 -> bf16 prepass. Wq (w==0) pre-scaled by log2(e)/8 so the
// attention softmax works in exp2 domain with zero epilogue cost in mm_qkv.
// ---------------------------------------------------------------------------
__global__ __launch_bounds__(256) void tobf16(
    const float* __restrict__ X, const float* __restrict__ W0,
    const float* __restrict__ W1, const float* __restrict__ W2,
    const float* __restrict__ W3,
    unsigned short* __restrict__ xb, unsigned short* __restrict__ wb)
{
    const size_t i = ((size_t)blockIdx.x * 256 + threadIdx.x) * 8;
    const size_t NX = (size_t)8388608;
    const float* src; unsigned short* dst; size_t off;
    float sc = 1.0f;
    if (i < NX) { src = X; dst = xb; off = i; }
    else {
        const size_t j = i - NX;
        const int w = (int)(j >> 20);
        off = j & 1048575;
        src = (w == 0) ? W0 : (w == 1) ? W1 : (w == 2) ? W2 : W3;
        dst = wb + ((size_t)w << 20);
        if (w == 0) sc = 0.180336880f;   // log2(e)/sqrt(64) folded into Wq
    }
    const float4 a = *reinterpret_cast<const float4*>(src + off);
    const float4 b = *reinterpret_cast<const float4*>(src + off + 4);
    short8 v;
    v[0] = (short)f2bfu(a.x * sc); v[1] = (short)f2bfu(a.y * sc);
    v[2] = (short)f2bfu(a.z * sc); v[3] = (short)f2bfu(a.w * sc);
    v[4] = (short)f2bfu(b.x * sc); v[5] = (short)f2bfu(b.y * sc);
    v[6] = (short)f2bfu(b.z * sc); v[7] = (short)f2bfu(b.w * sc);
    *reinterpret_cast<short8*>(dst + off) = v;
}

// ---------------------------------------------------------------------------
// Fragment-order layouts (per bh block of 131072 ushorts):
//  Q/K (A-frag over [s,d]): off = (s>>4)*1024 + (d>>5)*512 + ((d>>3)&3)*128
//                                 + (s&15)*8 + (d&7)
//  V   (A-frag over [d,s]): off = (s>>6)*4096 + ((d>>4)&3)*1024 + ((s>>5)&1)*512
//                                 + ((s>>3)&3)*128 + (d&15)*8 + (s&7)
// ---------------------------------------------------------------------------

// LDS XOR swizzle (ERRATA #21): linear LDS dest (global_load_lds), source
// col-slot XOR'd by row&7 at staging, ds_read slot (ks*4+g)^(c&7).

// ---------------------------------------------------------------------------
// Kernel 1: QKV projection GEMM (z = 0:Q / 1:K / 2:V^T).
// Operand order per-z so each lane's 4 acc values are CONSECUTIVE in the
// fragment layout -> epilogue = 2 cvt_pk + one 8B store per (mt,nt).
// r20-verified (166us best).
// ---------------------------------------------------------------------------
__global__ __launch_bounds__(256) void mm_qkv(
    const unsigned short* __restrict__ Ab, const unsigned short* __restrict__ Wall,
    unsigned short* __restrict__ oq, unsigned short* __restrict__ ok,
    unsigned short* __restrict__ ovt)
{
    __shared__ unsigned short As[2][128 * 64];
    __shared__ unsigned short Bs[2][128 * 64];

    const int z = blockIdx.z;
    const unsigned short* W = Wall + ((size_t)z << 20);

    const int m0 = blockIdx.x * 128, n0 = blockIdx.y * 128;
    const int t = threadIdx.x, lane = t & 63, wave = t >> 6;
    const int g = lane >> 4, c = lane & 15;
    const int wm = wave >> 1, wn = wave & 1;
    const int r8 = lane >> 3, c8 = lane & 7;
    const int ss = (c8 ^ (r8 & 7)) * 8;     // swizzled source slot (elems)

    f32x4 acc[4][4] = {};

#define STAGE_QKV(KT, BUF)                                                      \
    {                                                                           \
        const int kb_ = (KT) * 64;                                              \
        _Pragma("unroll")                                                       \
        for (int p = 0; p < 4; ++p) {                                           \
            const int rowb = wave * 8 + p * 32;                                 \
            __builtin_amdgcn_global_load_lds(                                   \
                (const __attribute__((address_space(1))) unsigned int*)(        \
                    Ab + (size_t)(m0 + rowb + r8) * 1024 + kb_ + ss),           \
                (__attribute__((address_space(3))) unsigned int*)(&As[BUF][rowb * 64]), 16, 0, 0); \
            __builtin_amdgcn_global_load_lds(                                   \
                (const __attribute__((address_space(1))) unsigned int*)(        \
                    W + (size_t)(n0 + rowb + r8) * 1024 + kb_ + ss),            \
                (__attribute__((address_space(3))) unsigned int*)(&Bs[BUF][rowb * 64]), 16, 0, 0); \
        }                                                                       \
    }

    STAGE_QKV(0, 0);
    __syncthreads();

#pragma unroll 1
    for (int kt = 0; kt < 16; ++kt) {
        const int cur = kt & 1;
        if (kt < 15) STAGE_QKV(kt + 1, cur ^ 1);

        if (z != 2) {
#pragma unroll
            for (int ks = 0; ks < 2; ++ks) {
                const int sa = ((ks * 4 + g) ^ (c & 7)) * 8;   // swizzled read slot
                short8 bf[4];
#pragma unroll
                for (int nt = 0; nt < 4; ++nt)
                    bf[nt] = *reinterpret_cast<const short8*>(&Bs[cur][(wn * 64 + nt * 16 + c) * 64 + sa]);
#pragma unroll
                for (int mt = 0; mt < 4; ++mt) {
                    const short8 af = *reinterpret_cast<const short8*>(&As[cur][(wm * 64 + mt * 16 + c) * 64 + sa]);
#pragma unroll
                    for (int nt = 0; nt < 4; ++nt)
                        acc[mt][nt] = __builtin_amdgcn_mfma_f32_16x16x32_bf16(bf[nt], af, acc[mt][nt], 0, 0, 0);
                }
            }
        } else {
#pragma unroll
            for (int ks = 0; ks < 2; ++ks) {
                const int sa = ((ks * 4 + g) ^ (c & 7)) * 8;
                short8 bf[4];
#pragma unroll
                for (int nt = 0; nt < 4; ++nt)
                    bf[nt] = *reinterpret_cast<const short8*>(&Bs[cur][(wn * 64 + nt * 16 + c) * 64 + sa]);
#pragma unroll
                for (int mt = 0; mt < 4; ++mt) {
                    const short8 af = *reinterpret_cast<const short8*>(&As[cur][(wm * 64 + mt * 16 + c) * 64 + sa]);
#pragma unroll
                    for (int nt = 0; nt < 4; ++nt)
                        acc[mt][nt] = __builtin_amdgcn_mfma_f32_16x16x32_bf16(af, bf[nt], acc[mt][nt], 0, 0, 0);
                }
            }
        }
        __syncthreads();
    }
#undef STAGE_QKV

    if (z != 2) {
        unsigned short* out = z ? ok : oq;
#pragma unroll
        for (int mt = 0; mt < 4; ++mt)
#pragma unroll
            for (int nt = 0; nt < 4; ++nt) {
                const int m = m0 + wm * 64 + mt * 16 + c;
                const int n = n0 + wn * 64 + nt * 16 + g * 4;     // r = 0..3
                const int bb = m >> 11, sl = m & 2047;
                const int h = n >> 6, d0 = n & 63;
                const size_t off = (size_t)(bb * Hq + h) * 131072
                    + (sl >> 4) * 1024 + (d0 >> 5) * 512 + ((d0 >> 3) & 3) * 128
                    + (sl & 15) * 8 + (d0 & 7);
                uint2v u;
                u[0] = cvtpk(acc[mt][nt][0], acc[mt][nt][1]);
                u[1] = cvtpk(acc[mt][nt][2], acc[mt][nt][3]);
                *reinterpret_cast<uint2v*>(&out[off]) = u;
            }
    } else {
#pragma unroll
        for (int mt = 0; mt < 4; ++mt)
#pragma unroll
            for (int nt = 0; nt < 4; ++nt) {
                const int m = m0 + wm * 64 + mt * 16 + g * 4;     // r = 0..3
                const int n = n0 + wn * 64 + nt * 16 + c;
                const int bb = m >> 11, sl = m & 2047;
                const int h = n >> 6, d = n & 63;
                const size_t off = (size_t)(bb * Hq + h) * 131072
                    + (sl >> 6) * 4096 + ((d >> 4) & 3) * 1024 + ((sl >> 5) & 1) * 512
                    + ((sl >> 3) & 3) * 128 + (d & 15) * 8 + (sl & 7);
                uint2v u;
                u[0] = cvtpk(acc[mt][nt][0], acc[mt][nt][1]);
                u[1] = cvtpk(acc[mt][nt][2], acc[mt][nt][3]);
                *reinterpret_cast<uint2v*>(&ovt[off]) = u;
            }
    }
}

// ---------------------------------------------------------------------------
// Kernel 2: causal flash attention.
// r20 structure + two de-serialization micro-opts:
//  (1) per-q-tile Pt slots (Pt[8][2][16][72]) so pack(B)'s LDS writes no
//      longer wait on pack(A)'s reads (same-wave LDS ordering) — the two
//      exp2/pack chains interleave;
//  (2) vf fragments loaded right after QK, before the packs, so their LDS
//      reads are in flight under the exp2 VALU chain.
// LDS 69.6KB -> still 2 co-resident blocks/CU with exact pairing.
// ---------------------------------------------------------------------------
static __device__ __forceinline__ void stage_kv8(
    const unsigned short* __restrict__ Kb, const unsigned short* __restrict__ Vb,
    int kb, unsigned short* kl, unsigned short* vl, int wave, int lane)
{
    const int off = wave * 512 + lane * 8;
    __builtin_amdgcn_global_load_lds(
        (const __attribute__((address_space(1))) unsigned int*)(Kb + (size_t)kb * 4096 + off),
        (__attribute__((address_space(3))) unsigned int*)(kl + wave * 512), 16, 0, 0);
    __builtin_amdgcn_global_load_lds(
        (const __attribute__((address_space(1))) unsigned int*)(Vb + (size_t)kb * 4096 + off),
        (__attribute__((address_space(3))) unsigned int*)(vl + wave * 512), 16, 0, 0);
}

static __device__ __forceinline__ void pack_p(
    f32x4* st, int rel, int g, int c, unsigned short (*PtW)[72],
    short8& pb0, short8& pb1)
{
    if (rel < 4) {
        const int lim = rel * 16 + c;
#pragma unroll
        for (int kt = 0; kt < 4; ++kt)
#pragma unroll
            for (int r = 0; r < 4; ++r)
                if (kt * 16 + g * 4 + r > lim) st[kt][r] = -3.0e38f;
    }
#pragma unroll
    for (int kt = 0; kt < 4; ++kt) {
        uint2v u;
        u[0] = cvtpk(exp2f(st[kt][0]), exp2f(st[kt][1]));
        u[1] = cvtpk(exp2f(st[kt][2]), exp2f(st[kt][3]));
        *reinterpret_cast<uint2v*>(&PtW[c][kt * 16 + g * 4]) = u;
    }
    pb0 = *reinterpret_cast<const short8*>(&PtW[c][g * 8]);
    pb1 = *reinterpret_cast<const short8*>(&PtW[c][32 + g * 8]);
}

__global__ __launch_bounds__(512, 2) void attn(
    const unsigned short* __restrict__ Qf, const unsigned short* __restrict__ Kf,
    const unsigned short* __restrict__ Vf, unsigned short* __restrict__ O)
{
    __shared__ unsigned short Kl[2][4096];
    __shared__ unsigned short Vl[2][4096];
    __shared__ unsigned short Pt[8][2][16][72];   // per-q-tile slots

    const int bid = blockIdx.x;
    const int half = bid >> 8;
    const int idx = (bid >> 6) & 3;
    const int qq = half ? (3 - idx) : (4 + idx);
    const int bh = (bid & 7) | (((bid >> 3) & 7) << 3);

    const int t = threadIdx.x, lane = t & 63, wave = t >> 6;
    const int g = lane >> 4, c = lane & 15;
    const size_t base = (size_t)bh * (Sq * DHq);
    const unsigned short* Qb = Qf + base;
    const unsigned short* Kb = Kf + base;
    const unsigned short* Vb = Vf + base;
    const int b = bh >> 4, h = bh & 15;

    short8 onesf;
#pragma unroll
    for (int j = 0; j < 8; ++j) onesf[j] = (short)0x3F80;

    const int qtA = qq * 16 + wave * 2;
    const int qtB = qtA + 1;

    const unsigned short* qpA = Qb + (size_t)qtA * 1024 + lane * 8;
    const unsigned short* qpB = Qb + (size_t)qtB * 1024 + lane * 8;
    const short8 qA0 = *reinterpret_cast<const short8*>(qpA);
    const short8 qA1 = *reinterpret_cast<const short8*>(qpA + 512);
    const short8 qB0 = *reinterpret_cast<const short8*>(qpB);
    const short8 qB1 = *reinterpret_cast<const short8*>(qpB + 512);

    f32x4 oA[4] = {}, oB[4] = {};
    f32x4 lA = {}, lB = {};

    const int ibmax = 4 * qq + 3;

    stage_kv8(Kb, Vb, 0, Kl[0], Vl[0], wave, lane);
    __syncthreads();

#pragma unroll 1
    for (int ib = 0; ib <= ibmax; ++ib) {
        const int cur = ib & 1;
        if (ib < ibmax)
            stage_kv8(Kb, Vb, ib + 1, Kl[cur ^ 1], Vl[cur ^ 1], wave, lane);
        __builtin_amdgcn_sched_barrier(0);

        if (4 * ib <= qtA) {
            const unsigned short* kl = &Kl[cur][lane * 8];
            const unsigned short* vl = &Vl[cur][lane * 8];

            f32x4 stA[4] = {}, stB[4] = {};
            __builtin_amdgcn_s_setprio(1);
#pragma unroll
            for (int k2 = 0; k2 < 4; ++k2) {
                const short8 kf0 = *reinterpret_cast<const short8*>(&kl[(2 * k2) * 512]);
                const short8 kf1 = *reinterpret_cast<const short8*>(&kl[(2 * k2 + 1) * 512]);
                stA[k2] = __builtin_amdgcn_mfma_f32_16x16x32_bf16(kf0, qA0, stA[k2], 0, 0, 0);
                stA[k2] = __builtin_amdgcn_mfma_f32_16x16x32_bf16(kf1, qA1, stA[k2], 0, 0, 0);
                stB[k2] = __builtin_amdgcn_mfma_f32_16x16x32_bf16(kf0, qB0, stB[k2], 0, 0, 0);
                stB[k2] = __builtin_amdgcn_mfma_f32_16x16x32_bf16(kf1, qB1, stB[k2], 0, 0, 0);
            }
            __builtin_amdgcn_s_setprio(0);

            // issue V reads early: they complete under the exp2/pack VALU
            short8 vf[8];
#pragma unroll
            for (int i = 0; i < 8; ++i)
                vf[i] = *reinterpret_cast<const short8*>(&vl[i * 512]);

            short8 pbA0, pbA1, pbB0, pbB1;
            pack_p(stA, qtA - 4 * ib, g, c, Pt[wave][0], pbA0, pbA1);
            pack_p(stB, qtB - 4 * ib, g, c, Pt[wave][1], pbB0, pbB1);

            __builtin_amdgcn_s_setprio(1);
            lA = __builtin_amdgcn_mfma_f32_16x16x32_bf16(onesf, pbA0, lA, 0, 0, 0);
            lA = __builtin_amdgcn_mfma_f32_16x16x32_bf16(onesf, pbA1, lA, 0, 0, 0);
            lB = __builtin_amdgcn_mfma_f32_16x16x32_bf16(onesf, pbB0, lB, 0, 0, 0);
            lB = __builtin_amdgcn_mfma_f32_16x16x32_bf16(onesf, pbB1, lB, 0, 0, 0);

#pragma unroll
            for (int dt = 0; dt < 4; ++dt) {
                oA[dt] = __builtin_amdgcn_mfma_f32_16x16x32_bf16(vf[2 * dt],     pbA0, oA[dt], 0, 0, 0);
                oA[dt] = __builtin_amdgcn_mfma_f32_16x16x32_bf16(vf[2 * dt + 1], pbA1, oA[dt], 0, 0, 0);
                oB[dt] = __builtin_amdgcn_mfma_f32_16x16x32_bf16(vf[2 * dt],     pbB0, oB[dt], 0, 0, 0);
                oB[dt] = __builtin_amdgcn_mfma_f32_16x16x32_bf16(vf[2 * dt + 1], pbB1, oB[dt], 0, 0, 0);
            }
            __builtin_amdgcn_s_setprio(0);
        }
        __syncthreads();
    }

    const float rlA = 1.0f / lA[0];
    const float rlB = 1.0f / lB[0];
    const size_t orowA = ((size_t)b * Sq + qtA * 16 + c) * Dq + h * 64;
    const size_t orowB = ((size_t)b * Sq + qtB * 16 + c) * Dq + h * 64;
#pragma unroll
    for (int dt = 0; dt < 4; ++dt) {
        uint2v uA, uB;
        uA[0] = cvtpk(oA[dt][0] * rlA, oA[dt][1] * rlA);
        uA[1] = cvtpk(oA[dt][2] * rlA, oA[dt][3] * rlA);
        uB[0] = cvtpk(oB[dt][0] * rlB, oB[dt][1] * rlB);
        uB[1] = cvtpk(oB[dt][2] * rlB, oB[dt][3] * rlB);
        *reinterpret_cast<uint2v*>(&O[orowA + dt * 16 + g * 4]) = uA;
        *reinterpret_cast<uint2v*>(&O[orowB + dt * 16 + g * 4]) = uB;
    }
}

// ---------------------------------------------------------------------------
// Kernel 3: output projection, SWAPPED mfma -> one float4 store per (mt,nt).
// r20-verified. out = Z*Wo^T + bo.
// ---------------------------------------------------------------------------
__global__ __launch_bounds__(256) void mm_o(
    const unsigned short* __restrict__ Ab, const unsigned short* __restrict__ Wall,
    const float* __restrict__ bo, float* __restrict__ outf)
{
    __shared__ unsigned short As[2][128 * 64];
    __shared__ unsigned short Bs[2][128 * 64];

    const unsigned short* W = Wall + ((size_t)3 << 20);

    const int m0 = blockIdx.x * 128, n0 = blockIdx.y * 128;
    const int t = threadIdx.x, lane = t & 63, wave = t >> 6;
    const int g = lane >> 4, c = lane & 15;
    const int wm = wave >> 1, wn = wave & 1;
    const int r8 = lane >> 3, c8 = lane & 7;
    const int ss = (c8 ^ (r8 & 7)) * 8;

    f32x4 acc[4][4] = {};

#define STAGE_O(KT, BUF)                                                        \
    {                                                                           \
        const int kb_ = (KT) * 64;                                              \
        _Pragma("unroll")                                                       \
        for (int p = 0; p < 4; ++p) {                                           \
            const int rowb = wave * 8 + p * 32;                                 \
            __builtin_amdgcn_global_load_lds(                                   \
                (const __attribute__((address_space(1))) unsigned int*)(        \
                    Ab + (size_t)(m0 + rowb + r8) * 1024 + kb_ + ss),           \
                (__attribute__((address_space(3))) unsigned int*)(&As[BUF][rowb * 64]), 16, 0, 0); \
            __builtin_amdgcn_global_load_lds(                                   \
                (const __attribute__((address_space(1))) unsigned int*)(        \
                    W + (size_t)(n0 + rowb + r8) * 1024 + kb_ + ss),            \
                (__attribute__((address_space(3))) unsigned int*)(&Bs[BUF][rowb * 64]), 16, 0, 0); \
        }                                                                       \
    }

    STAGE_O(0, 0);
    __syncthreads();

#pragma unroll 1
    for (int kt = 0; kt < 16; ++kt) {
        const int cur = kt & 1;
        if (kt < 15) STAGE_O(kt + 1, cur ^ 1);

#pragma unroll
        for (int ks = 0; ks < 2; ++ks) {
            const int sa = ((ks * 4 + g) ^ (c & 7)) * 8;
            short8 bf[4];
#pragma unroll
            for (int nt = 0; nt < 4; ++nt)
                bf[nt] = *reinterpret_cast<const short8*>(&Bs[cur][(wn * 64 + nt * 16 + c) * 64 + sa]);
#pragma unroll
            for (int mt = 0; mt < 4; ++mt) {
                const short8 af = *reinterpret_cast<const short8*>(&As[cur][(wm * 64 + mt * 16 + c) * 64 + sa]);
#pragma unroll
                for (int nt = 0; nt < 4; ++nt)
                    acc[mt][nt] = __builtin_amdgcn_mfma_f32_16x16x32_bf16(bf[nt], af, acc[mt][nt], 0, 0, 0);
            }
        }
        __syncthreads();
    }
#undef STAGE_O

#pragma unroll
    for (int mt = 0; mt < 4; ++mt) {
        const int m = m0 + wm * 64 + mt * 16 + c;
#pragma unroll
        for (int nt = 0; nt < 4; ++nt) {
            const int nb = n0 + wn * 64 + nt * 16 + g * 4;
            const float4 b4 = *reinterpret_cast<const float4*>(&bo[nb]);
            float4 v;
            v.x = acc[mt][nt][0] + b4.x;
            v.y = acc[mt][nt][1] + b4.y;
            v.z = acc[mt][nt][2] + b4.z;
            v.w = acc[mt][nt][3] + b4.w;
            *reinterpret_cast<float4*>(&outf[(size_t)m * 1024 + nb]) = v;
        }
    }
}

// ---------------------------------------------------------------------------
extern "C" void kernel_launch(void* const* d_in, const int* in_sizes, int n_in,
                              void* d_out, int out_size, void* d_ws, size_t ws_size,
                              hipStream_t stream) {
    const float* X  = (const float*)d_in[0];
    const float* Wq = (const float*)d_in[1];
    const float* Wk = (const float*)d_in[2];
    const float* Wv = (const float*)d_in[3];
    const float* Wo = (const float*)d_in[4];
    const float* bo = (const float*)d_in[5];
    float* out = (float*)d_out;

    const size_t elems = (size_t)Bq * Hq * Sq * DHq;  // 8,388,608
    unsigned short* q  = (unsigned short*)d_ws;
    unsigned short* k  = q + elems;
    unsigned short* vt = k + elems;
    unsigned short* xo = vt + elems;        // Xb during GEMMs, attn-output after
    unsigned short* wb = xo + elems;        // 4 bf16 weight matrices
    // total ws: 5*16MB + 8MB = 72MB

    tobf16<<<dim3(6144), 256, 0, stream>>>(X, Wq, Wk, Wv, Wo, xo, wb);

    mm_qkv<<<dim3(64, 8, 3), 256, 0, stream>>>(xo, wb, q, k, vt);

    attn<<<dim3(512), 512, 0, stream>>>(q, k, vt, xo);

    mm_o<<<dim3(64, 8, 1), 256, 0, stream>>>(xo, wb, bo, out);
}

// Round 22
// 166.035 us; speedup vs baseline: 1.0403x; 1.0403x over previous
//
#include <hip/hip_runtime.h>
#include <hip/hip_bf16.h>

// MHA forward: B=4, S=2048, D=1024, H=16, DH=64. fp32 in/out, bf16 MFMA inside.

#define Bq 4
#define Sq 2048
#define Dq 1024
#define Hq 16
#define DHq 64

typedef __attribute__((ext_vector_type(8))) short short8;
typedef __attribute__((ext_vector_type(4))) float f32x4;
typedef __attribute__((ext_vector_type(2))) unsigned int uint2v;

static __device__ __forceinline__ unsigned short f2bfu(float f) {
    union { __hip_bfloat16 h; unsigned short u; } cv;
    cv.h = __float2bfloat16(f);
    return cv.u;
}
static __device__ __forceinline__ unsigned int cvtpk(float lo, float hi) {
    unsigned int r;
    asm("v_cvt_pk_bf16_f32 %0, %1, %2" : "=v"(r) : "v"(lo), "v"(hi));
    return r;
}

// ---------------------------------------------------------------------------
// Kernel 0: fp32 -> bf16 prepass. Wq (w==0) pre-scaled by log2(e)/8 so the
// attention softmax works in exp2 domain with zero epilogue cost in mm_qkv.
// ---------------------------------------------------------------------------
__global__ __launch_bounds__(256) void tobf16(
    const float* __restrict__ X, const float* __restrict__ W0,
    const float* __restrict__ W1, const float* __restrict__ W2,
    const float* __restrict__ W3,
    unsigned short* __restrict__ xb, unsigned short* __restrict__ wb)
{
    const size_t i = ((size_t)blockIdx.x * 256 + threadIdx.x) * 8;
    const size_t NX = (size_t)8388608;
    const float* src; unsigned short* dst; size_t off;
    float sc = 1.0f;
    if (i < NX) { src = X; dst = xb; off = i; }
    else {
        const size_t j = i - NX;
        const int w = (int)(j >> 20);
        off = j & 1048575;
        src = (w == 0) ? W0 : (w == 1) ? W1 : (w == 2) ? W2 : W3;
        dst = wb + ((size_t)w << 20);
        if (w == 0) sc = 0.180336880f;   // log2(e)/sqrt(64) folded into Wq
    }
    const float4 a = *reinterpret_cast<const float4*>(src + off);
    const float4 b = *reinterpret_cast<const float4*>(src + off + 4);
    short8 v;
    v[0] = (short)f2bfu(a.x * sc); v[1] = (short)f2bfu(a.y * sc);
    v[2] = (short)f2bfu(a.z * sc); v[3] = (short)f2bfu(a.w * sc);
    v[4] = (short)f2bfu(b.x * sc); v[5] = (short)f2bfu(b.y * sc);
    v[6] = (short)f2bfu(b.z * sc); v[7] = (short)f2bfu(b.w * sc);
    *reinterpret_cast<short8*>(dst + off) = v;
}

// ---------------------------------------------------------------------------
// Fragment-order layouts (per bh block of 131072 ushorts):
//  Q/K (A-frag over [s,d]): off = (s>>4)*1024 + (d>>5)*512 + ((d>>3)&3)*128
//                                 + (s&15)*8 + (d&7)
//  V   (A-frag over [d,s]): off = (s>>6)*4096 + ((d>>4)&3)*1024 + ((s>>5)&1)*512
//                                 + ((s>>3)&3)*128 + (d&15)*8 + (s&7)
// ---------------------------------------------------------------------------

// LDS XOR swizzle (ERRATA #21): linear LDS dest (global_load_lds), source
// col-slot XOR'd by row&7 at staging, ds_read slot (ks*4+g)^(c&7).

// ---------------------------------------------------------------------------
// Kernel 1: QKV projection GEMM (z = 0:Q / 1:K / 2:V^T).
// Operand order per-z so each lane's 4 acc values are CONSECUTIVE in the
// fragment layout -> epilogue = 2 cvt_pk + one 8B store per (mt,nt).
// r20-verified (166us best).
// ---------------------------------------------------------------------------
__global__ __launch_bounds__(256) void mm_qkv(
    const unsigned short* __restrict__ Ab, const unsigned short* __restrict__ Wall,
    unsigned short* __restrict__ oq, unsigned short* __restrict__ ok,
    unsigned short* __restrict__ ovt)
{
    __shared__ unsigned short As[2][128 * 64];
    __shared__ unsigned short Bs[2][128 * 64];

    const int z = blockIdx.z;
    const unsigned short* W = Wall + ((size_t)z << 20);

    const int m0 = blockIdx.x * 128, n0 = blockIdx.y * 128;
    const int t = threadIdx.x, lane = t & 63, wave = t >> 6;
    const int g = lane >> 4, c = lane & 15;
    const int wm = wave >> 1, wn = wave & 1;
    const int r8 = lane >> 3, c8 = lane & 7;
    const int ss = (c8 ^ (r8 & 7)) * 8;     // swizzled source slot (elems)

    f32x4 acc[4][4] = {};

#define STAGE_QKV(KT, BUF)                                                      \
    {                                                                           \
        const int kb_ = (KT) * 64;                                              \
        _Pragma("unroll")                                                       \
        for (int p = 0; p < 4; ++p) {                                           \
            const int rowb = wave * 8 + p * 32;                                 \
            __builtin_amdgcn_global_load_lds(                                   \
                (const __attribute__((address_space(1))) unsigned int*)(        \
                    Ab + (size_t)(m0 + rowb + r8) * 1024 + kb_ + ss),           \
                (__attribute__((address_space(3))) unsigned int*)(&As[BUF][rowb * 64]), 16, 0, 0); \
            __builtin_amdgcn_global_load_lds(                                   \
                (const __attribute__((address_space(1))) unsigned int*)(        \
                    W + (size_t)(n0 + rowb + r8) * 1024 + kb_ + ss),            \
                (__attribute__((address_space(3))) unsigned int*)(&Bs[BUF][rowb * 64]), 16, 0, 0); \
        }                                                                       \
    }

    STAGE_QKV(0, 0);
    __syncthreads();

#pragma unroll 1
    for (int kt = 0; kt < 16; ++kt) {
        const int cur = kt & 1;
        if (kt < 15) STAGE_QKV(kt + 1, cur ^ 1);

        if (z != 2) {
#pragma unroll
            for (int ks = 0; ks < 2; ++ks) {
                const int sa = ((ks * 4 + g) ^ (c & 7)) * 8;   // swizzled read slot
                short8 bf[4];
#pragma unroll
                for (int nt = 0; nt < 4; ++nt)
                    bf[nt] = *reinterpret_cast<const short8*>(&Bs[cur][(wn * 64 + nt * 16 + c) * 64 + sa]);
#pragma unroll
                for (int mt = 0; mt < 4; ++mt) {
                    const short8 af = *reinterpret_cast<const short8*>(&As[cur][(wm * 64 + mt * 16 + c) * 64 + sa]);
#pragma unroll
                    for (int nt = 0; nt < 4; ++nt)
                        acc[mt][nt] = __builtin_amdgcn_mfma_f32_16x16x32_bf16(bf[nt], af, acc[mt][nt], 0, 0, 0);
                }
            }
        } else {
#pragma unroll
            for (int ks = 0; ks < 2; ++ks) {
                const int sa = ((ks * 4 + g) ^ (c & 7)) * 8;
                short8 bf[4];
#pragma unroll
                for (int nt = 0; nt < 4; ++nt)
                    bf[nt] = *reinterpret_cast<const short8*>(&Bs[cur][(wn * 64 + nt * 16 + c) * 64 + sa]);
#pragma unroll
                for (int mt = 0; mt < 4; ++mt) {
                    const short8 af = *reinterpret_cast<const short8*>(&As[cur][(wm * 64 + mt * 16 + c) * 64 + sa]);
#pragma unroll
                    for (int nt = 0; nt < 4; ++nt)
                        acc[mt][nt] = __builtin_amdgcn_mfma_f32_16x16x32_bf16(af, bf[nt], acc[mt][nt], 0, 0, 0);
                }
            }
        }
        __syncthreads();
    }
#undef STAGE_QKV

    if (z != 2) {
        // swapped: token = m0+wm*64+mt*16+c ; feature = n0+wn*64+nt*16+g*4+r
        unsigned short* out = z ? ok : oq;
#pragma unroll
        for (int mt = 0; mt < 4; ++mt)
#pragma unroll
            for (int nt = 0; nt < 4; ++nt) {
                const int m = m0 + wm * 64 + mt * 16 + c;
                const int n = n0 + wn * 64 + nt * 16 + g * 4;     // r = 0..3
                const int bb = m >> 11, sl = m & 2047;
                const int h = n >> 6, d0 = n & 63;
                const size_t off = (size_t)(bb * Hq + h) * 131072
                    + (sl >> 4) * 1024 + (d0 >> 5) * 512 + ((d0 >> 3) & 3) * 128
                    + (sl & 15) * 8 + (d0 & 7);
                uint2v u;
                u[0] = cvtpk(acc[mt][nt][0], acc[mt][nt][1]);
                u[1] = cvtpk(acc[mt][nt][2], acc[mt][nt][3]);
                *reinterpret_cast<uint2v*>(&out[off]) = u;
            }
    } else {
        // unswapped: token = m0+wm*64+mt*16+g*4+r ; feature = n0+wn*64+nt*16+c
#pragma unroll
        for (int mt = 0; mt < 4; ++mt)
#pragma unroll
            for (int nt = 0; nt < 4; ++nt) {
                const int m = m0 + wm * 64 + mt * 16 + g * 4;     // r = 0..3
                const int n = n0 + wn * 64 + nt * 16 + c;
                const int bb = m >> 11, sl = m & 2047;
                const int h = n >> 6, d = n & 63;
                const size_t off = (size_t)(bb * Hq + h) * 131072
                    + (sl >> 6) * 4096 + ((d >> 4) & 3) * 1024 + ((sl >> 5) & 1) * 512
                    + ((sl >> 3) & 3) * 128 + (d & 15) * 8 + (sl & 7);
                uint2v u;
                u[0] = cvtpk(acc[mt][nt][0], acc[mt][nt][1]);
                u[1] = cvtpk(acc[mt][nt][2], acc[mt][nt][3]);
                *reinterpret_cast<uint2v*>(&ovt[off]) = u;
            }
    }
}

// ---------------------------------------------------------------------------
// Kernel 2: causal flash attention (r16/r20-verified structure, 72us).
// LDS-shared K/V, 8-wave blocks, 2 co-resident blocks/CU with exact pairing;
// joint stA/stB with transient kf reads; single Pt; on-demand vf reads.
// ---------------------------------------------------------------------------
static __device__ __forceinline__ void stage_kv8(
    const unsigned short* __restrict__ Kb, const unsigned short* __restrict__ Vb,
    int kb, unsigned short* kl, unsigned short* vl, int wave, int lane)
{
    const int off = wave * 512 + lane * 8;
    __builtin_amdgcn_global_load_lds(
        (const __attribute__((address_space(1))) unsigned int*)(Kb + (size_t)kb * 4096 + off),
        (__attribute__((address_space(3))) unsigned int*)(kl + wave * 512), 16, 0, 0);
    __builtin_amdgcn_global_load_lds(
        (const __attribute__((address_space(1))) unsigned int*)(Vb + (size_t)kb * 4096 + off),
        (__attribute__((address_space(3))) unsigned int*)(vl + wave * 512), 16, 0, 0);
}

static __device__ __forceinline__ void pack_p(
    f32x4* st, int rel, int g, int c, unsigned short (*PtW)[72],
    short8& pb0, short8& pb1)
{
    if (rel < 4) {
        const int lim = rel * 16 + c;
#pragma unroll
        for (int kt = 0; kt < 4; ++kt)
#pragma unroll
            for (int r = 0; r < 4; ++r)
                if (kt * 16 + g * 4 + r > lim) st[kt][r] = -3.0e38f;
    }
#pragma unroll
    for (int kt = 0; kt < 4; ++kt) {
        uint2v u;
        u[0] = cvtpk(exp2f(st[kt][0]), exp2f(st[kt][1]));
        u[1] = cvtpk(exp2f(st[kt][2]), exp2f(st[kt][3]));
        *reinterpret_cast<uint2v*>(&PtW[c][kt * 16 + g * 4]) = u;
    }
    pb0 = *reinterpret_cast<const short8*>(&PtW[c][g * 8]);
    pb1 = *reinterpret_cast<const short8*>(&PtW[c][32 + g * 8]);
}

__global__ __launch_bounds__(512, 2) void attn(
    const unsigned short* __restrict__ Qf, const unsigned short* __restrict__ Kf,
    const unsigned short* __restrict__ Vf, unsigned short* __restrict__ O)
{
    __shared__ unsigned short Kl[2][4096];
    __shared__ unsigned short Vl[2][4096];
    __shared__ unsigned short Pt[8][16][72];

    const int bid = blockIdx.x;
    const int half = bid >> 8;
    const int idx = (bid >> 6) & 3;
    const int qq = half ? (3 - idx) : (4 + idx);
    const int bh = (bid & 7) | (((bid >> 3) & 7) << 3);

    const int t = threadIdx.x, lane = t & 63, wave = t >> 6;
    const int g = lane >> 4, c = lane & 15;
    const size_t base = (size_t)bh * (Sq * DHq);
    const unsigned short* Qb = Qf + base;
    const unsigned short* Kb = Kf + base;
    const unsigned short* Vb = Vf + base;
    const int b = bh >> 4, h = bh & 15;

    short8 onesf;
#pragma unroll
    for (int j = 0; j < 8; ++j) onesf[j] = (short)0x3F80;

    const int qtA = qq * 16 + wave * 2;
    const int qtB = qtA + 1;

    const unsigned short* qpA = Qb + (size_t)qtA * 1024 + lane * 8;
    const unsigned short* qpB = Qb + (size_t)qtB * 1024 + lane * 8;
    const short8 qA0 = *reinterpret_cast<const short8*>(qpA);
    const short8 qA1 = *reinterpret_cast<const short8*>(qpA + 512);
    const short8 qB0 = *reinterpret_cast<const short8*>(qpB);
    const short8 qB1 = *reinterpret_cast<const short8*>(qpB + 512);

    f32x4 oA[4] = {}, oB[4] = {};
    f32x4 lA = {}, lB = {};

    const int ibmax = 4 * qq + 3;

    stage_kv8(Kb, Vb, 0, Kl[0], Vl[0], wave, lane);
    __syncthreads();

#pragma unroll 1
    for (int ib = 0; ib <= ibmax; ++ib) {
        const int cur = ib & 1;
        if (ib < ibmax)
            stage_kv8(Kb, Vb, ib + 1, Kl[cur ^ 1], Vl[cur ^ 1], wave, lane);
        __builtin_amdgcn_sched_barrier(0);

        if (4 * ib <= qtA) {
            const unsigned short* kl = &Kl[cur][lane * 8];
            const unsigned short* vl = &Vl[cur][lane * 8];

            f32x4 stA[4] = {}, stB[4] = {};
            __builtin_amdgcn_s_setprio(1);
#pragma unroll
            for (int k2 = 0; k2 < 4; ++k2) {
                const short8 kf0 = *reinterpret_cast<const short8*>(&kl[(2 * k2) * 512]);
                const short8 kf1 = *reinterpret_cast<const short8*>(&kl[(2 * k2 + 1) * 512]);
                stA[k2] = __builtin_amdgcn_mfma_f32_16x16x32_bf16(kf0, qA0, stA[k2], 0, 0, 0);
                stA[k2] = __builtin_amdgcn_mfma_f32_16x16x32_bf16(kf1, qA1, stA[k2], 0, 0, 0);
                stB[k2] = __builtin_amdgcn_mfma_f32_16x16x32_bf16(kf0, qB0, stB[k2], 0, 0, 0);
                stB[k2] = __builtin_amdgcn_mfma_f32_16x16x32_bf16(kf1, qB1, stB[k2], 0, 0, 0);
            }
            __builtin_amdgcn_s_setprio(0);

            short8 pbA0, pbA1, pbB0, pbB1;
            pack_p(stA, qtA - 4 * ib, g, c, Pt[wave], pbA0, pbA1);
            pack_p(stB, qtB - 4 * ib, g, c, Pt[wave], pbB0, pbB1);

            __builtin_amdgcn_s_setprio(1);
            lA = __builtin_amdgcn_mfma_f32_16x16x32_bf16(onesf, pbA0, lA, 0, 0, 0);
            lA = __builtin_amdgcn_mfma_f32_16x16x32_bf16(onesf, pbA1, lA, 0, 0, 0);
            lB = __builtin_amdgcn_mfma_f32_16x16x32_bf16(onesf, pbB0, lB, 0, 0, 0);
            lB = __builtin_amdgcn_mfma_f32_16x16x32_bf16(onesf, pbB1, lB, 0, 0, 0);

#pragma unroll
            for (int dt = 0; dt < 4; ++dt) {
                const short8 vf0 = *reinterpret_cast<const short8*>(&vl[(2 * dt) * 512]);
                const short8 vf1 = *reinterpret_cast<const short8*>(&vl[(2 * dt + 1) * 512]);
                oA[dt] = __builtin_amdgcn_mfma_f32_16x16x32_bf16(vf0, pbA0, oA[dt], 0, 0, 0);
                oA[dt] = __builtin_amdgcn_mfma_f32_16x16x32_bf16(vf1, pbA1, oA[dt], 0, 0, 0);
                oB[dt] = __builtin_amdgcn_mfma_f32_16x16x32_bf16(vf0, pbB0, oB[dt], 0, 0, 0);
                oB[dt] = __builtin_amdgcn_mfma_f32_16x16x32_bf16(vf1, pbB1, oB[dt], 0, 0, 0);
            }
            __builtin_amdgcn_s_setprio(0);
        }
        __syncthreads();
    }

    const float rlA = 1.0f / lA[0];
    const float rlB = 1.0f / lB[0];
    const size_t orowA = ((size_t)b * Sq + qtA * 16 + c) * Dq + h * 64;
    const size_t orowB = ((size_t)b * Sq + qtB * 16 + c) * Dq + h * 64;
#pragma unroll
    for (int dt = 0; dt < 4; ++dt) {
        uint2v uA, uB;
        uA[0] = cvtpk(oA[dt][0] * rlA, oA[dt][1] * rlA);
        uA[1] = cvtpk(oA[dt][2] * rlA, oA[dt][3] * rlA);
        uB[0] = cvtpk(oB[dt][0] * rlB, oB[dt][1] * rlB);
        uB[1] = cvtpk(oB[dt][2] * rlB, oB[dt][3] * rlB);
        *reinterpret_cast<uint2v*>(&O[orowA + dt * 16 + g * 4]) = uA;
        *reinterpret_cast<uint2v*>(&O[orowB + dt * 16 + g * 4]) = uB;
    }
}

// ---------------------------------------------------------------------------
// Kernel 3: output projection, SWAPPED mfma -> one float4 store per (mt,nt).
// r20-verified. out = Z*Wo^T + bo.
// ---------------------------------------------------------------------------
__global__ __launch_bounds__(256) void mm_o(
    const unsigned short* __restrict__ Ab, const unsigned short* __restrict__ Wall,
    const float* __restrict__ bo, float* __restrict__ outf)
{
    __shared__ unsigned short As[2][128 * 64];
    __shared__ unsigned short Bs[2][128 * 64];

    const unsigned short* W = Wall + ((size_t)3 << 20);

    const int m0 = blockIdx.x * 128, n0 = blockIdx.y * 128;
    const int t = threadIdx.x, lane = t & 63, wave = t >> 6;
    const int g = lane >> 4, c = lane & 15;
    const int wm = wave >> 1, wn = wave & 1;
    const int r8 = lane >> 3, c8 = lane & 7;
    const int ss = (c8 ^ (r8 & 7)) * 8;

    f32x4 acc[4][4] = {};

#define STAGE_O(KT, BUF)                                                        \
    {                                                                           \
        const int kb_ = (KT) * 64;                                              \
        _Pragma("unroll")                                                       \
        for (int p = 0; p < 4; ++p) {                                           \
            const int rowb = wave * 8 + p * 32;                                 \
            __builtin_amdgcn_global_load_lds(                                   \
                (const __attribute__((address_space(1))) unsigned int*)(        \
                    Ab + (size_t)(m0 + rowb + r8) * 1024 + kb_ + ss),           \
                (__attribute__((address_space(3))) unsigned int*)(&As[BUF][rowb * 64]), 16, 0, 0); \
            __builtin_amdgcn_global_load_lds(                                   \
                (const __attribute__((address_space(1))) unsigned int*)(        \
                    W + (size_t)(n0 + rowb + r8) * 1024 + kb_ + ss),            \
                (__attribute__((address_space(3))) unsigned int*)(&Bs[BUF][rowb * 64]), 16, 0, 0); \
        }                                                                       \
    }

    STAGE_O(0, 0);
    __syncthreads();

#pragma unroll 1
    for (int kt = 0; kt < 16; ++kt) {
        const int cur = kt & 1;
        if (kt < 15) STAGE_O(kt + 1, cur ^ 1);

#pragma unroll
        for (int ks = 0; ks < 2; ++ks) {
            const int sa = ((ks * 4 + g) ^ (c & 7)) * 8;
            short8 bf[4];
#pragma unroll
            for (int nt = 0; nt < 4; ++nt)
                bf[nt] = *reinterpret_cast<const short8*>(&Bs[cur][(wn * 64 + nt * 16 + c) * 64 + sa]);
#pragma unroll
            for (int mt = 0; mt < 4; ++mt) {
                const short8 af = *reinterpret_cast<const short8*>(&As[cur][(wm * 64 + mt * 16 + c) * 64 + sa]);
#pragma unroll
                for (int nt = 0; nt < 4; ++nt)
                    acc[mt][nt] = __builtin_amdgcn_mfma_f32_16x16x32_bf16(bf[nt], af, acc[mt][nt], 0, 0, 0);
            }
        }
        __syncthreads();
    }
#undef STAGE_O

    // swapped: row m = m0+wm*64+mt*16+c ; cols nb..nb+3 = n0+wn*64+nt*16+g*4+r
#pragma unroll
    for (int mt = 0; mt < 4; ++mt) {
        const int m = m0 + wm * 64 + mt * 16 + c;
#pragma unroll
        for (int nt = 0; nt < 4; ++nt) {
            const int nb = n0 + wn * 64 + nt * 16 + g * 4;
            const float4 b4 = *reinterpret_cast<const float4*>(&bo[nb]);
            float4 v;
            v.x = acc[mt][nt][0] + b4.x;
            v.y = acc[mt][nt][1] + b4.y;
            v.z = acc[mt][nt][2] + b4.z;
            v.w = acc[mt][nt][3] + b4.w;
            *reinterpret_cast<float4*>(&outf[(size_t)m * 1024 + nb]) = v;
        }
    }
}

// ---------------------------------------------------------------------------
extern "C" void kernel_launch(void* const* d_in, const int* in_sizes, int n_in,
                              void* d_out, int out_size, void* d_ws, size_t ws_size,
                              hipStream_t stream) {
    const float* X  = (const float*)d_in[0];
    const float* Wq = (const float*)d_in[1];
    const float* Wk = (const float*)d_in[2];
    const float* Wv = (const float*)d_in[3];
    const float* Wo = (const float*)d_in[4];
    const float* bo = (const float*)d_in[5];
    float* out = (float*)d_out;

    const size_t elems = (size_t)Bq * Hq * Sq * DHq;  // 8,388,608
    unsigned short* q  = (unsigned short*)d_ws;
    unsigned short* k  = q + elems;
    unsigned short* vt = k + elems;
    unsigned short* xo = vt + elems;        // Xb during GEMMs, attn-output after
    unsigned short* wb = xo + elems;        // 4 bf16 weight matrices
    // total ws: 5*16MB + 8MB = 72MB

    tobf16<<<dim3(6144), 256, 0, stream>>>(X, Wq, Wk, Wv, Wo, xo, wb);

    mm_qkv<<<dim3(64, 8, 3), 256, 0, stream>>>(xo, wb, q, k, vt);

    attn<<<dim3(512), 512, 0, stream>>>(q, k, vt, xo);

    mm_o<<<dim3(64, 8, 1), 256, 0, stream>>>(xo, wb, bo, out);
}